// Round 13
// baseline (1307.070 us; speedup 1.0000x reference)
//
#include <hip/hip_runtime.h>

#define NB  64
#define IC  2048
#define ID  16
#define DD  256
#define DDSQ 65536
#define PB  (DDSQ * NB)       // 4,194,304 floats = one full-batch fp32-sized buffer
#define NSQ 11                // matrix squarings
#define NPI 7                 // finish matvecs: exponent 2^11 * 8 = 16384

typedef __attribute__((ext_vector_type(8))) short          s16x8;  // 8 bf16 (4 VGPRs) MFMA frag
typedef __attribute__((ext_vector_type(4))) float          f32x4;  // MFMA acc
typedef __attribute__((ext_vector_type(4))) unsigned short us4;
typedef __attribute__((ext_vector_type(8))) unsigned short us8;

// fp32 -> bf16 (RNE) and back, via raw bits
__device__ __forceinline__ unsigned short f2b(float f) {
    union { float f; unsigned u; } c; c.f = f;
    const unsigned u = c.u + 0x7FFFu + ((c.u >> 16) & 1u);
    return (unsigned short)(u >> 16);
}
__device__ __forceinline__ float b2f(unsigned short h) {
    union { unsigned u; float f; } c; c.u = ((unsigned)h) << 16;
    return c.f;
}
// fp32 -> packed (hi bf16 << 16) | (lo bf16): 2-term split in one u32
__device__ __forceinline__ unsigned f2pk(float f) {
    const unsigned short h = f2b(f);
    const unsigned short l = f2b(f - b2f(h));
    return ((unsigned)h << 16) | (unsigned)l;
}

// ---------------- stage 1: u[b,c,:] = x[b,c,:] @ W_c (ALL 64 batches/block) -
// One block per capsule c (2048 blocks): W row read ONCE (round-10 proven).
__global__ __launch_bounds__(256, 4) void u_kernel(const float* __restrict__ caps,
                                                   const float* __restrict__ W,
                                                   unsigned* __restrict__ U) {
    const int c = blockIdx.x;
    const int t = threadIdx.x;
    __shared__ float xsT[ID][64];        // [dim][batch] (4 KB)
    {
        const int b = t >> 2, q = (t & 3) * 4;
        const float4 x4 = *(const float4*)&caps[((size_t)b * IC + c) * ID + q];
        xsT[q + 0][b] = x4.x; xsT[q + 1][b] = x4.y;
        xsT[q + 2][b] = x4.z; xsT[q + 3][b] = x4.w;
    }
    __syncthreads();
    float a[64];
#pragma unroll
    for (int b = 0; b < 64; ++b) a[b] = 0.f;
#pragma unroll
    for (int i = 0; i < ID; ++i) {
        const float wi = W[((size_t)c * ID + i) * DD + t];    // coalesced over t
#pragma unroll
        for (int g = 0; g < 16; ++g) {
            const float4 x = *(const float4*)&xsT[i][g * 4];
            a[g * 4 + 0] = fmaf(x.x, wi, a[g * 4 + 0]);
            a[g * 4 + 1] = fmaf(x.y, wi, a[g * 4 + 1]);
            a[g * 4 + 2] = fmaf(x.z, wi, a[g * 4 + 2]);
            a[g * 4 + 3] = fmaf(x.w, wi, a[g * 4 + 3]);
        }
    }
#pragma unroll
    for (int b = 0; b < 64; ++b)
        U[((size_t)b * IC + c) * DD + t] = f2pk(a[b]);
}

// ---- stage 2: C = U^T U (full K), BK=32, bf16 hi/lo out + trace ------------
// EXACT round-10/12-proven body.
__global__ __launch_bounds__(256, 2)
void cmb_kernel(const unsigned* __restrict__ Up,
                unsigned short* __restrict__ Ch, unsigned short* __restrict__ Cl,
                float* __restrict__ Sc) {
    const int id   = blockIdx.x;
    const int bb   = id & 63;
    const int tile = id >> 6;            // 0..7 (2x4 of 128x64)
    const int tr = tile >> 2, tc = tile & 3;
    const int d0 = tr * 128, e0 = tc * 64;
    const int t    = threadIdx.x;
    const int lane = t & 63, wid = t >> 6;
    const int wm = wid >> 1, wn = wid & 1;            // 2x2 wave grid
    const int fr = lane & 15, kg = lane >> 4;         // frag row, k-group
    const int sl8 = lane & 7, qg = lane >> 3;         // staging: row-in-octet, k-quad
    const size_t mb = (size_t)bb * DDSQ;

    __shared__ unsigned short Ah[128][40];   // [d][k], pitch 40 shorts (80 B)
    __shared__ unsigned short Al[128][40];
    __shared__ unsigned short Bh[64][40];    // [e][k]
    __shared__ unsigned short Bl[64][40];
    __shared__ float red[256];

    const f32x4 z4 = {0.f, 0.f, 0.f, 0.f};
    f32x4 acc[4][2];
#pragma unroll
    for (int m = 0; m < 4; ++m)
#pragma unroll
        for (int n = 0; n < 2; ++n) acc[m][n] = z4;

    const unsigned* Ub = Up + (size_t)bb * IC * DD;
    unsigned va[4][4], vb[2][4];
    auto loadU = [&](int kb) {
#pragma unroll
        for (int s = 0; s < 4; ++s) {
            const int row = wid * 8 + sl8 + 32 * s;       // d-local 0..127
#pragma unroll
            for (int j = 0; j < 4; ++j)
                va[s][j] = Ub[(size_t)(kb + 4 * qg + j) * DD + d0 + row];
        }
#pragma unroll
        for (int s = 0; s < 2; ++s) {
            const int row = wid * 8 + sl8 + 32 * s;       // e-local 0..63
#pragma unroll
            for (int j = 0; j < 4; ++j)
                vb[s][j] = Ub[(size_t)(kb + 4 * qg + j) * DD + e0 + row];
        }
    };

    loadU(0);
    for (int kb = 0; kb < IC; kb += 32) {
        __syncthreads();
#pragma unroll
        for (int s = 0; s < 4; ++s) {
            const int row = wid * 8 + sl8 + 32 * s;
            us4 h, l;
#pragma unroll
            for (int j = 0; j < 4; ++j) {
                h[j] = (unsigned short)(va[s][j] >> 16);
                l[j] = (unsigned short)(va[s][j] & 0xFFFFu);
            }
            *(us4*)&Ah[row][4 * qg] = h;
            *(us4*)&Al[row][4 * qg] = l;
        }
#pragma unroll
        for (int s = 0; s < 2; ++s) {
            const int row = wid * 8 + sl8 + 32 * s;
            us4 h, l;
#pragma unroll
            for (int j = 0; j < 4; ++j) {
                h[j] = (unsigned short)(vb[s][j] >> 16);
                l[j] = (unsigned short)(vb[s][j] & 0xFFFFu);
            }
            *(us4*)&Bh[row][4 * qg] = h;
            *(us4*)&Bl[row][4 * qg] = l;
        }
        __syncthreads();
        if (kb + 32 < IC) loadU(kb + 32);     // T14: next loads fly under MFMA
        s16x8 ah[4], al[4], bh[2], bl[2];
#pragma unroll
        for (int m = 0; m < 4; ++m) {
            const int r = wm * 64 + m * 16 + fr;
            ah[m] = *(const s16x8*)&Ah[r][kg * 8];
            al[m] = *(const s16x8*)&Al[r][kg * 8];
        }
#pragma unroll
        for (int n = 0; n < 2; ++n) {
            const int r = wn * 32 + n * 16 + fr;
            bh[n] = *(const s16x8*)&Bh[r][kg * 8];
            bl[n] = *(const s16x8*)&Bl[r][kg * 8];
        }
#pragma unroll
        for (int m = 0; m < 4; ++m)
#pragma unroll
            for (int n = 0; n < 2; ++n) {
                acc[m][n] = __builtin_amdgcn_mfma_f32_16x16x32_bf16(ah[m], bh[n], acc[m][n], 0, 0, 0);
                acc[m][n] = __builtin_amdgcn_mfma_f32_16x16x32_bf16(ah[m], bl[n], acc[m][n], 0, 0, 0);
                acc[m][n] = __builtin_amdgcn_mfma_f32_16x16x32_bf16(al[m], bh[n], acc[m][n], 0, 0, 0);
            }
    }

    // epilogue: bf16 hi/lo store (UNSCALED C) + fp32 trace
    float ts = 0.f;
    const int row_l = wm * 64 + (lane >> 4) * 4;
    const int col_l = wn * 32 + fr;
#pragma unroll
    for (int m = 0; m < 4; ++m)
#pragma unroll
        for (int n = 0; n < 2; ++n)
#pragma unroll
            for (int r = 0; r < 4; ++r) {
                const int gr = d0 + row_l + m * 16 + r;
                const int gc = e0 + col_l + n * 16;
                const float e = acc[m][n][r];
                const unsigned short h = f2b(e);
                const unsigned short l = f2b(e - b2f(h));
                const size_t o = mb + (size_t)gr * DD + gc;
                Ch[o] = h; Cl[o] = l;
                if (gr == gc) ts += e;
            }
    if ((tc >> 1) == tr) {
        red[t] = ts;
        __syncthreads();
        for (int s2 = 128; s2 > 0; s2 >>= 1) {
            if (t < s2) red[t] += red[t + s2];
            __syncthreads();
        }
        if (t == 0) atomicAdd(&Sc[bb], red[0]);
    }
}

// ---- fused squaring chain + finish: persistent 512 blocks ------------------
// Plain launch (NOT cooperative — that API failed under graph capture, R4).
// __launch_bounds__(256,2) + 38 KB LDS guarantee 2 blocks/CU => all 512
// co-resident (capacity == grid, no deadlock). Grid barrier from verified
// primitives: device-scope atomicAdd (m20) + __threadfence release/acquire.
// Monotonic counter (no reset race); zeroed by host memset each replay.
// Per squaring each block runs 2 of 1024 tile-jobs (exact R11 BK=64 body,
// bit-identical arithmetic), then barrier; blocks 0..63 run finish inline.
__device__ __forceinline__ void grid_sync(unsigned* bar, unsigned target) {
    __syncthreads();
    if (threadIdx.x == 0) {
        __threadfence();                              // release: flush our writes
        atomicAdd(bar, 1u);                           // device-scope arrive
        while (atomicAdd(bar, 0u) < target)           // device-coherent poll
            __builtin_amdgcn_s_sleep(64);             // ~4k clk backoff
    }
    __syncthreads();
    __threadfence();                                  // acquire: invalidate caches
}

__global__ __launch_bounds__(256, 2)
void sqc_kernel(unsigned short* __restrict__ Xh, unsigned short* __restrict__ Xl,
                unsigned short* __restrict__ Yh, unsigned short* __restrict__ Yl,
                float* __restrict__ Sc, unsigned* __restrict__ bar,
                float* __restrict__ out) {
    const int blk  = blockIdx.x;          // 0..511
    const int t    = threadIdx.x;
    const int lane = t & 63, wid = t >> 6;
    const int wm = wid >> 1, wn = wid & 1;            // 2x2 wave grid, 32x32/wave
    const int fr = lane & 15, kg = lane >> 4;
    const int row = t >> 2, q = t & 3;                // staging map
    const int bb = blk & 63;
    const size_t mb = (size_t)bb * DDSQ;

    __shared__ unsigned short Ah[64][72];   // pitch 72 shorts (144 B)
    __shared__ unsigned short Al[64][72];
    __shared__ unsigned short Bh[64][72];
    __shared__ unsigned short Bl[64][72];
    __shared__ float red[256];

    const f32x4 z4 = {0.f, 0.f, 0.f, 0.f};

    for (int it = 0; it < NSQ; ++it) {
        const unsigned short* dh = (it & 1) ? Yh : Xh;
        const unsigned short* dl = (it & 1) ? Yl : Xl;
        unsigned short* eh = (it & 1) ? Xh : Yh;
        unsigned short* el = (it & 1) ? Xl : Yl;
        const float s   = Sc[it * 64 + bb];
        const float inv = 1.f / (s * s);
        float* s_out = Sc + (it + 1) * 64;

#pragma unroll 1
        for (int j = 0; j < 2; ++j) {
            const int tile = (blk >> 6) + j * 8;      // 0..15
            const int tr = tile >> 2, tc = tile & 3;
            const int d0 = tr * 64, e0 = tc * 64;

            f32x4 acc[2][2];
#pragma unroll
            for (int m = 0; m < 2; ++m)
#pragma unroll
                for (int n = 0; n < 2; ++n) acc[m][n] = z4;

            for (int kb = 0; kb < DD; kb += 64) {
                const size_t ga = mb + (size_t)(d0 + row) * DD + kb + q * 8;
                const size_t gb = mb + (size_t)(e0 + row) * DD + kb + q * 8;
                const int4 rah0 = *(const int4*)&dh[ga];
                const int4 rah1 = *(const int4*)&dh[ga + 32];
                const int4 ral0 = *(const int4*)&dl[ga];
                const int4 ral1 = *(const int4*)&dl[ga + 32];
                const int4 rbh0 = *(const int4*)&dh[gb];
                const int4 rbh1 = *(const int4*)&dh[gb + 32];
                const int4 rbl0 = *(const int4*)&dl[gb];
                const int4 rbl1 = *(const int4*)&dl[gb + 32];
                __syncthreads();
                *(int4*)&Ah[row][q * 8]      = rah0;
                *(int4*)&Ah[row][q * 8 + 32] = rah1;
                *(int4*)&Al[row][q * 8]      = ral0;
                *(int4*)&Al[row][q * 8 + 32] = ral1;
                *(int4*)&Bh[row][q * 8]      = rbh0;
                *(int4*)&Bh[row][q * 8 + 32] = rbh1;
                *(int4*)&Bl[row][q * 8]      = rbl0;
                *(int4*)&Bl[row][q * 8 + 32] = rbl1;
                __syncthreads();

#pragma unroll
                for (int h = 0; h < 2; ++h) {
                    const int ko = kg * 8 + 32 * h;
                    s16x8 ah[2], al[2], bh[2], bl[2];
#pragma unroll
                    for (int m = 0; m < 2; ++m) {
                        const int r = wm * 32 + m * 16 + fr;
                        ah[m] = *(const s16x8*)&Ah[r][ko];
                        al[m] = *(const s16x8*)&Al[r][ko];
                    }
#pragma unroll
                    for (int n = 0; n < 2; ++n) {
                        const int r = wn * 32 + n * 16 + fr;
                        bh[n] = *(const s16x8*)&Bh[r][ko];
                        bl[n] = *(const s16x8*)&Bl[r][ko];
                    }
#pragma unroll
                    for (int m = 0; m < 2; ++m)
#pragma unroll
                        for (int n = 0; n < 2; ++n) {
                            acc[m][n] = __builtin_amdgcn_mfma_f32_16x16x32_bf16(ah[m], bh[n], acc[m][n], 0, 0, 0);
                            acc[m][n] = __builtin_amdgcn_mfma_f32_16x16x32_bf16(ah[m], bl[n], acc[m][n], 0, 0, 0);
                            acc[m][n] = __builtin_amdgcn_mfma_f32_16x16x32_bf16(al[m], bh[n], acc[m][n], 0, 0, 0);
                        }
                }
            }

            // epilogue: scale, trace, split to hi/lo bf16
            float ts = 0.f;
            const int row_l = wm * 32 + (lane >> 4) * 4;
            const int col_l = wn * 32 + fr;
#pragma unroll
            for (int m = 0; m < 2; ++m)
#pragma unroll
                for (int n = 0; n < 2; ++n)
#pragma unroll
                    for (int r = 0; r < 4; ++r) {
                        const int gr = d0 + row_l + m * 16 + r;
                        const int gc = e0 + col_l + n * 16;
                        const float e = acc[m][n][r] * inv;
                        const unsigned short h = f2b(e);
                        const unsigned short l = f2b(e - b2f(h));
                        const size_t o = mb + (size_t)gr * DD + gc;
                        eh[o] = h; el[o] = l;
                        if (gr == gc) ts += e;
                    }
            if (tr == tc) {               // 4 diag tiles partition the diagonal
                red[t] = ts;
                __syncthreads();
                for (int s2 = 128; s2 > 0; s2 >>= 1) {
                    if (t < s2) red[t] += red[t + s2];
                    __syncthreads();
                }
                if (t == 0) atomicAdd(&s_out[bb], red[0]);
            }
        }
        grid_sync(bar, 512u * (unsigned)(it + 1));
    }

    // -------- fused finish: blocks 0..63; final matrix in Y (it=10 even) ----
    if (blk < 64) {
        const unsigned short* Fh = Yh;
        const unsigned short* Fl = Yl;
        const size_t fb = (size_t)blk * DDSQ;
        float* vs  = (float*)&Ah[0][0];
        int*  ridx = (int*)&Bh[0][0];
        red[t] = b2f(Fh[fb + (size_t)t * DD + t]) + b2f(Fl[fb + (size_t)t * DD + t]);
        ridx[t] = t;
        __syncthreads();
        for (int s2 = 128; s2 > 0; s2 >>= 1) {
            if (t < s2 && red[t + s2] > red[t]) { red[t] = red[t + s2]; ridx[t] = ridx[t + s2]; }
            __syncthreads();
        }
        const int jmax0 = ridx[0];
        __syncthreads();
        float v = b2f(Fh[fb + (size_t)jmax0 * DD + t]) + b2f(Fl[fb + (size_t)jmax0 * DD + t]);
        for (int itv = 0; itv < NPI; ++itv) {
            vs[t] = v;
            __syncthreads();
            float a = 0.f;
            const unsigned short* rh = Fh + fb + (size_t)t * DD;
            const unsigned short* rl = Fl + fb + (size_t)t * DD;
#pragma unroll 4
            for (int j = 0; j < DD; j += 8) {
                const us8 h8 = *(const us8*)&rh[j];
                const us8 l8 = *(const us8*)&rl[j];
                a = fmaf(b2f(h8[0]) + b2f(l8[0]), vs[j + 0], a);
                a = fmaf(b2f(h8[1]) + b2f(l8[1]), vs[j + 1], a);
                a = fmaf(b2f(h8[2]) + b2f(l8[2]), vs[j + 2], a);
                a = fmaf(b2f(h8[3]) + b2f(l8[3]), vs[j + 3], a);
                a = fmaf(b2f(h8[4]) + b2f(l8[4]), vs[j + 4], a);
                a = fmaf(b2f(h8[5]) + b2f(l8[5]), vs[j + 5], a);
                a = fmaf(b2f(h8[6]) + b2f(l8[6]), vs[j + 6], a);
                a = fmaf(b2f(h8[7]) + b2f(l8[7]), vs[j + 7], a);
            }
            __syncthreads();
            v = a;
        }
        vs[t] = v;
        red[t] = v * v;
        __syncthreads();
        for (int s2 = 128; s2 > 0; s2 >>= 1) {
            if (t < s2) red[t] += red[t + s2];
            __syncthreads();
        }
        const float nrm = sqrtf(red[0]);
        __syncthreads();
        red[t] = fabsf(v);
        ridx[t] = t;
        __syncthreads();
        for (int s2 = 128; s2 > 0; s2 >>= 1) {
            if (t < s2 && red[t + s2] > red[t]) { red[t] = red[t + s2]; ridx[t] = ridx[t + s2]; }
            __syncthreads();
        }
        const float sgn = (vs[ridx[0]] < 0.f) ? -1.f : 1.f;
        out[(size_t)blk * DD + t] = sgn * v / nrm;
    }
}

extern "C" void kernel_launch(void* const* d_in, const int* in_sizes, int n_in,
                              void* d_out, int out_size, void* d_ws, size_t ws_size,
                              hipStream_t stream) {
    const float* caps = (const float*)d_in[0];   // (64, 2048, 16)
    const float* W    = (const float*)d_in[1];   // (2048, 16, 256)
    float* out = (float*)d_out;                  // (64, 256)
    float* ws  = (float*)d_ws;

    // layout: Up packed = 8*PB @0 | X @8PB | Y @9PB | Sc @10PB  (~168 MB)
    unsigned* Up = (unsigned*)ws;
    unsigned short* Xh = (unsigned short*)(ws + (size_t)8 * PB);
    unsigned short* Xl = Xh + (size_t)NB * DDSQ;
    unsigned short* Yh = (unsigned short*)(ws + (size_t)9 * PB);
    unsigned short* Yl = Yh + (size_t)NB * DDSQ;
    float* Sc = ws + (size_t)10 * PB;
    unsigned* bar = (unsigned*)(Sc + 1024);      // inside the zeroed 2048-float region

    hipMemsetAsync(Sc, 0, 2048 * sizeof(float), stream);

    u_kernel<<<IC, 256, 0, stream>>>(caps, W, Up);
    cmb_kernel<<<512, 256, 0, stream>>>(Up, Xh, Xl, Sc);   // C (unscaled) -> X

    sqc_kernel<<<512, 256, 0, stream>>>(Xh, Xl, Yh, Yl, Sc, bar, out);
}

// Round 14
// 372.338 us; speedup vs baseline: 3.5104x; 3.5104x over previous
//
#include <hip/hip_runtime.h>

#define NB  64
#define IC  2048
#define ID  16
#define DD  256
#define DDSQ 65536
#define PB  (DDSQ * NB)       // 4,194,304 floats = one full-batch fp32-sized buffer
#define NSQ 11                // matrix squarings
#define NPI 7                 // finish matvecs: exponent 2^11 * 8 = 16384

typedef __attribute__((ext_vector_type(8))) short          s16x8;  // 8 bf16 (4 VGPRs) MFMA frag
typedef __attribute__((ext_vector_type(4))) float          f32x4;  // MFMA acc
typedef __attribute__((ext_vector_type(4))) unsigned short us4;
typedef __attribute__((ext_vector_type(8))) unsigned short us8;

// fp32 -> bf16 (RNE) and back, via raw bits
__device__ __forceinline__ unsigned short f2b(float f) {
    union { float f; unsigned u; } c; c.f = f;
    const unsigned u = c.u + 0x7FFFu + ((c.u >> 16) & 1u);
    return (unsigned short)(u >> 16);
}
__device__ __forceinline__ float b2f(unsigned short h) {
    union { unsigned u; float f; } c; c.u = ((unsigned)h) << 16;
    return c.f;
}
// fp32 -> packed (hi bf16 << 16) | (lo bf16): 2-term split in one u32
__device__ __forceinline__ unsigned f2pk(float f) {
    const unsigned short h = f2b(f);
    const unsigned short l = f2b(f - b2f(h));
    return ((unsigned)h << 16) | (unsigned)l;
}

// ---------------- stage 1: u[b,c,:] = x[b,c,:] @ W_c (ALL 64 batches/block) -
// One block per capsule c (2048 blocks): W row read ONCE (round-10 proven).
__global__ __launch_bounds__(256, 4) void u_kernel(const float* __restrict__ caps,
                                                   const float* __restrict__ W,
                                                   unsigned* __restrict__ U) {
    const int c = blockIdx.x;
    const int t = threadIdx.x;
    __shared__ float xsT[ID][64];        // [dim][batch] (4 KB)
    {
        const int b = t >> 2, q = (t & 3) * 4;
        const float4 x4 = *(const float4*)&caps[((size_t)b * IC + c) * ID + q];
        xsT[q + 0][b] = x4.x; xsT[q + 1][b] = x4.y;
        xsT[q + 2][b] = x4.z; xsT[q + 3][b] = x4.w;
    }
    __syncthreads();
    float a[64];
#pragma unroll
    for (int b = 0; b < 64; ++b) a[b] = 0.f;
#pragma unroll
    for (int i = 0; i < ID; ++i) {
        const float wi = W[((size_t)c * ID + i) * DD + t];    // coalesced over t
#pragma unroll
        for (int g = 0; g < 16; ++g) {
            const float4 x = *(const float4*)&xsT[i][g * 4];
            a[g * 4 + 0] = fmaf(x.x, wi, a[g * 4 + 0]);
            a[g * 4 + 1] = fmaf(x.y, wi, a[g * 4 + 1]);
            a[g * 4 + 2] = fmaf(x.z, wi, a[g * 4 + 2]);
            a[g * 4 + 3] = fmaf(x.w, wi, a[g * 4 + 3]);
        }
    }
#pragma unroll
    for (int b = 0; b < 64; ++b)
        U[((size_t)b * IC + c) * DD + t] = f2pk(a[b]);
}

// ---- stage 2: C = U^T U, 64x64 tiles, UPPER TRIANGLE (640 blocks) ----------
// C is bit-exactly symmetric (IEEE mul commutes, same k-order) => compute 10
// tiles (tr<=tc), mirror the 6 off-diagonal ones (R12-sqm-proven pattern).
// 64-row register-transpose staging = cmb's own proven B-panel map; BK=32,
// pitch-40 LDS (R10-proven). LDS 21.5 KB -> ~3 blocks/CU (was 2 at 31.7 KB).
// Per-element k-chain identical to the 128x64 version => bit-identical C.
__global__ __launch_bounds__(256, 4)
void cm64_kernel(const unsigned* __restrict__ Up,
                 unsigned short* __restrict__ Ch, unsigned short* __restrict__ Cl,
                 float* __restrict__ Sc) {
    const int id   = blockIdx.x;          // 640 = 64 batches x 10 tri-tiles
    const int bb   = id & 63;
    const int tile = id >> 6;             // 0..9 upper-triangle enumeration
    int tr, tc;
    if (tile < 4)      { tr = 0; tc = tile; }
    else if (tile < 7) { tr = 1; tc = tile - 3; }
    else if (tile < 9) { tr = 2; tc = tile - 5; }
    else               { tr = 3; tc = 3; }
    const int d0 = tr * 64, e0 = tc * 64;
    const int t    = threadIdx.x;
    const int lane = t & 63, wid = t >> 6;
    const int wm = wid >> 1, wn = wid & 1;            // 2x2 wave grid, 32x32/wave
    const int fr = lane & 15, kg = lane >> 4;         // frag row, k-group
    const int sl8 = lane & 7, qg = lane >> 3;         // staging: row-in-octet, k-quad
    const size_t mb = (size_t)bb * DDSQ;

    __shared__ unsigned short Ah[64][40];   // [d][k], pitch 40 shorts (80 B)
    __shared__ unsigned short Al[64][40];
    __shared__ unsigned short Bh[64][40];   // [e][k]
    __shared__ unsigned short Bl[64][40];
    __shared__ float red[256];

    const f32x4 z4 = {0.f, 0.f, 0.f, 0.f};
    f32x4 acc[2][2];
#pragma unroll
    for (int m = 0; m < 2; ++m)
#pragma unroll
        for (int n = 0; n < 2; ++n) acc[m][n] = z4;

    const unsigned* Ub = Up + (size_t)bb * IC * DD;
    unsigned va[2][4], vb[2][4];
    auto loadU = [&](int kb) {
#pragma unroll
        for (int s = 0; s < 2; ++s) {
            const int row = wid * 8 + sl8 + 32 * s;       // d-local 0..63
#pragma unroll
            for (int j = 0; j < 4; ++j)
                va[s][j] = Ub[(size_t)(kb + 4 * qg + j) * DD + d0 + row];
        }
#pragma unroll
        for (int s = 0; s < 2; ++s) {
            const int row = wid * 8 + sl8 + 32 * s;       // e-local 0..63
#pragma unroll
            for (int j = 0; j < 4; ++j)
                vb[s][j] = Ub[(size_t)(kb + 4 * qg + j) * DD + e0 + row];
        }
    };

    loadU(0);
    for (int kb = 0; kb < IC; kb += 32) {
        __syncthreads();
#pragma unroll
        for (int s = 0; s < 2; ++s) {
            const int row = wid * 8 + sl8 + 32 * s;
            us4 h, l;
#pragma unroll
            for (int j = 0; j < 4; ++j) {
                h[j] = (unsigned short)(va[s][j] >> 16);
                l[j] = (unsigned short)(va[s][j] & 0xFFFFu);
            }
            *(us4*)&Ah[row][4 * qg] = h;
            *(us4*)&Al[row][4 * qg] = l;
        }
#pragma unroll
        for (int s = 0; s < 2; ++s) {
            const int row = wid * 8 + sl8 + 32 * s;
            us4 h, l;
#pragma unroll
            for (int j = 0; j < 4; ++j) {
                h[j] = (unsigned short)(vb[s][j] >> 16);
                l[j] = (unsigned short)(vb[s][j] & 0xFFFFu);
            }
            *(us4*)&Bh[row][4 * qg] = h;
            *(us4*)&Bl[row][4 * qg] = l;
        }
        __syncthreads();
        if (kb + 32 < IC) loadU(kb + 32);     // T14: next loads fly under MFMA
        s16x8 ah[2], al[2], bh[2], bl[2];
#pragma unroll
        for (int m = 0; m < 2; ++m) {
            const int r = wm * 32 + m * 16 + fr;
            ah[m] = *(const s16x8*)&Ah[r][kg * 8];
            al[m] = *(const s16x8*)&Al[r][kg * 8];
        }
#pragma unroll
        for (int n = 0; n < 2; ++n) {
            const int r = wn * 32 + n * 16 + fr;
            bh[n] = *(const s16x8*)&Bh[r][kg * 8];
            bl[n] = *(const s16x8*)&Bl[r][kg * 8];
        }
#pragma unroll
        for (int m = 0; m < 2; ++m)
#pragma unroll
            for (int n = 0; n < 2; ++n) {
                acc[m][n] = __builtin_amdgcn_mfma_f32_16x16x32_bf16(ah[m], bh[n], acc[m][n], 0, 0, 0);
                acc[m][n] = __builtin_amdgcn_mfma_f32_16x16x32_bf16(ah[m], bl[n], acc[m][n], 0, 0, 0);
                acc[m][n] = __builtin_amdgcn_mfma_f32_16x16x32_bf16(al[m], bh[n], acc[m][n], 0, 0, 0);
            }
    }

    // epilogue: bf16 hi/lo store (UNSCALED C) + trace; mirror off-diag tiles
    float ts = 0.f;
    const int row_l = wm * 32 + (lane >> 4) * 4;
    const int col_l = wn * 32 + fr;
    const bool mir = (tr != tc);
#pragma unroll
    for (int m = 0; m < 2; ++m)
#pragma unroll
        for (int n = 0; n < 2; ++n) {
            const int gr0 = d0 + row_l + m * 16;
            const int gc  = e0 + col_l + n * 16;
            us4 h4, l4;
#pragma unroll
            for (int r = 0; r < 4; ++r) {
                const float e = acc[m][n][r];
                const unsigned short h = f2b(e);
                const unsigned short l = f2b(e - b2f(h));
                const size_t o = mb + (size_t)(gr0 + r) * DD + gc;
                Ch[o] = h; Cl[o] = l;
                h4[r] = h; l4[r] = l;
                if (gr0 + r == gc) ts += e;
            }
            if (mir) {                    // transposed us4: row gc, cols gr0..+3
                const size_t o2 = mb + (size_t)gc * DD + gr0;
                *(us4*)&Ch[o2] = h4;
                *(us4*)&Cl[o2] = l4;
            }
        }
    if (tr == tc) {                       // 4 diag tiles partition the diagonal
        red[t] = ts;
        __syncthreads();
        for (int s2 = 128; s2 > 0; s2 >>= 1) {
            if (t < s2) red[t] += red[t + s2];
            __syncthreads();
        }
        if (t == 0) atomicAdd(&Sc[bb], red[0]);
    }
}

// ---- E = (D/s)^2, 64x64 tile, BK=64, UPPER-TRIANGLE ONLY (640 blocks) ------
// EXACT round-12-proven body (bit-identical output, passed at 371 us).
__global__ __launch_bounds__(256, 4)
void sqm_kernel(const unsigned short* __restrict__ Dh, const unsigned short* __restrict__ Dl,
                unsigned short* __restrict__ Eh, unsigned short* __restrict__ El,
                const float* __restrict__ s_in, float* __restrict__ s_out) {
    const int id   = blockIdx.x;          // 640 = 64 batches x 10 tri-tiles
    const int bb   = id & 63;             // id%8 == bb%8 -> batch XCD-local
    const int tile = id >> 6;             // 0..9 upper-triangle enumeration
    int tr, tc;
    if (tile < 4)      { tr = 0; tc = tile; }
    else if (tile < 7) { tr = 1; tc = tile - 3; }
    else if (tile < 9) { tr = 2; tc = tile - 5; }
    else               { tr = 3; tc = 3; }
    const int d0 = tr * 64, e0 = tc * 64;
    const int t    = threadIdx.x;
    const int lane = t & 63, wid = t >> 6;
    const int wm = wid >> 1, wn = wid & 1;            // 2x2 wave grid, 32x32/wave
    const int fr = lane & 15, kg = lane >> 4;
    const size_t mb = (size_t)bb * DDSQ;

    __shared__ unsigned short Ah[64][72];   // pitch 72 shorts (144 B)
    __shared__ unsigned short Al[64][72];
    __shared__ unsigned short Bh[64][72];
    __shared__ unsigned short Bl[64][72];
    __shared__ float red[256];

    const f32x4 z4 = {0.f, 0.f, 0.f, 0.f};
    f32x4 acc[2][2];
#pragma unroll
    for (int m = 0; m < 2; ++m)
#pragma unroll
        for (int n = 0; n < 2; ++n) acc[m][n] = z4;

    const float s   = s_in[bb];
    const float inv = 1.f / (s * s);
    const int row = t >> 2, q = t & 3;    // staging map: 64 rows x 4 k-quads

    for (int kb = 0; kb < DD; kb += 64) {
        const size_t ga = mb + (size_t)(d0 + row) * DD + kb + q * 8;
        const size_t gb = mb + (size_t)(e0 + row) * DD + kb + q * 8;
        const int4 rah0 = *(const int4*)&Dh[ga];
        const int4 rah1 = *(const int4*)&Dh[ga + 32];
        const int4 ral0 = *(const int4*)&Dl[ga];
        const int4 ral1 = *(const int4*)&Dl[ga + 32];
        const int4 rbh0 = *(const int4*)&Dh[gb];
        const int4 rbh1 = *(const int4*)&Dh[gb + 32];
        const int4 rbl0 = *(const int4*)&Dl[gb];
        const int4 rbl1 = *(const int4*)&Dl[gb + 32];
        __syncthreads();
        *(int4*)&Ah[row][q * 8]      = rah0;
        *(int4*)&Ah[row][q * 8 + 32] = rah1;
        *(int4*)&Al[row][q * 8]      = ral0;
        *(int4*)&Al[row][q * 8 + 32] = ral1;
        *(int4*)&Bh[row][q * 8]      = rbh0;
        *(int4*)&Bh[row][q * 8 + 32] = rbh1;
        *(int4*)&Bl[row][q * 8]      = rbl0;
        *(int4*)&Bl[row][q * 8 + 32] = rbl1;
        __syncthreads();

#pragma unroll
        for (int h = 0; h < 2; ++h) {
            const int ko = kg * 8 + 32 * h;
            s16x8 ah[2], al[2], bh[2], bl[2];
#pragma unroll
            for (int m = 0; m < 2; ++m) {
                const int r = wm * 32 + m * 16 + fr;
                ah[m] = *(const s16x8*)&Ah[r][ko];
                al[m] = *(const s16x8*)&Al[r][ko];
            }
#pragma unroll
            for (int n = 0; n < 2; ++n) {
                const int r = wn * 32 + n * 16 + fr;
                bh[n] = *(const s16x8*)&Bh[r][ko];
                bl[n] = *(const s16x8*)&Bl[r][ko];
            }
#pragma unroll
            for (int m = 0; m < 2; ++m)
#pragma unroll
                for (int n = 0; n < 2; ++n) {
                    acc[m][n] = __builtin_amdgcn_mfma_f32_16x16x32_bf16(ah[m], bh[n], acc[m][n], 0, 0, 0);
                    acc[m][n] = __builtin_amdgcn_mfma_f32_16x16x32_bf16(ah[m], bl[n], acc[m][n], 0, 0, 0);
                    acc[m][n] = __builtin_amdgcn_mfma_f32_16x16x32_bf16(al[m], bh[n], acc[m][n], 0, 0, 0);
                }
        }
    }

    // epilogue: scale, trace, split to hi/lo bf16; mirror off-diag tiles
    float ts = 0.f;
    const int row_l = wm * 32 + (lane >> 4) * 4;
    const int col_l = wn * 32 + fr;
    const bool mir = (tr != tc);
#pragma unroll
    for (int m = 0; m < 2; ++m)
#pragma unroll
        for (int n = 0; n < 2; ++n) {
            const int gr0 = d0 + row_l + m * 16;
            const int gc  = e0 + col_l + n * 16;
            us4 h4, l4;
#pragma unroll
            for (int r = 0; r < 4; ++r) {
                const float e = acc[m][n][r] * inv;
                const unsigned short h = f2b(e);
                const unsigned short l = f2b(e - b2f(h));
                const size_t o = mb + (size_t)(gr0 + r) * DD + gc;
                Eh[o] = h; El[o] = l;
                h4[r] = h; l4[r] = l;
                if (gr0 + r == gc) ts += e;
            }
            if (mir) {                    // transposed us4: row gc, cols gr0..+3
                const size_t o2 = mb + (size_t)gc * DD + gr0;
                *(us4*)&Eh[o2] = h4;
                *(us4*)&El[o2] = l4;
            }
        }
    if (tr == tc) {                       // 4 diag tiles partition the diagonal
        red[t] = ts;
        __syncthreads();
        for (int s2 = 128; s2 > 0; s2 >>= 1) {
            if (t < s2) red[t] += red[t + s2];
            __syncthreads();
        }
        if (t == 0) atomicAdd(&s_out[bb], red[0]);
    }
}

// ------- finish: column start + NPI matvecs (no renorm; lambda1 ~ 1) --------
__global__ __launch_bounds__(256, 2) void finish_kernel(const unsigned short* __restrict__ Dh,
                                                        const unsigned short* __restrict__ Dl,
                                                        float* __restrict__ out) {
    const int b = blockIdx.x, t = threadIdx.x;
    const size_t mb = (size_t)b * DDSQ;
    __shared__ float vs[DD];
    __shared__ float red[DD];
    __shared__ int   ridx[DD];
    red[t] = b2f(Dh[mb + (size_t)t * DD + t]) + b2f(Dl[mb + (size_t)t * DD + t]);
    ridx[t] = t;
    __syncthreads();
    for (int s = 128; s > 0; s >>= 1) {
        if (t < s && red[t + s] > red[t]) { red[t] = red[t + s]; ridx[t] = ridx[t + s]; }
        __syncthreads();
    }
    const int jmax0 = ridx[0];
    __syncthreads();
    float v = b2f(Dh[mb + (size_t)jmax0 * DD + t]) + b2f(Dl[mb + (size_t)jmax0 * DD + t]);
    for (int it = 0; it < NPI; ++it) {
        vs[t] = v;
        __syncthreads();
        float a = 0.f;
        const unsigned short* rh = Dh + mb + (size_t)t * DD;
        const unsigned short* rl = Dl + mb + (size_t)t * DD;
#pragma unroll 4
        for (int j = 0; j < DD; j += 8) {
            const us8 h8 = *(const us8*)&rh[j];
            const us8 l8 = *(const us8*)&rl[j];
            a = fmaf(b2f(h8[0]) + b2f(l8[0]), vs[j + 0], a);
            a = fmaf(b2f(h8[1]) + b2f(l8[1]), vs[j + 1], a);
            a = fmaf(b2f(h8[2]) + b2f(l8[2]), vs[j + 2], a);
            a = fmaf(b2f(h8[3]) + b2f(l8[3]), vs[j + 3], a);
            a = fmaf(b2f(h8[4]) + b2f(l8[4]), vs[j + 4], a);
            a = fmaf(b2f(h8[5]) + b2f(l8[5]), vs[j + 5], a);
            a = fmaf(b2f(h8[6]) + b2f(l8[6]), vs[j + 6], a);
            a = fmaf(b2f(h8[7]) + b2f(l8[7]), vs[j + 7], a);
        }
        __syncthreads();
        v = a;
    }
    vs[t] = v;
    red[t] = v * v;
    __syncthreads();
    for (int s = 128; s > 0; s >>= 1) {
        if (t < s) red[t] += red[t + s];
        __syncthreads();
    }
    const float nrm = sqrtf(red[0]);
    __syncthreads();
    red[t] = fabsf(v);
    ridx[t] = t;
    __syncthreads();
    for (int s = 128; s > 0; s >>= 1) {
        if (t < s && red[t + s] > red[t]) { red[t] = red[t + s]; ridx[t] = ridx[t + s]; }
        __syncthreads();
    }
    const float sgn = (vs[ridx[0]] < 0.f) ? -1.f : 1.f;
    out[(size_t)b * DD + t] = sgn * v / nrm;
}

extern "C" void kernel_launch(void* const* d_in, const int* in_sizes, int n_in,
                              void* d_out, int out_size, void* d_ws, size_t ws_size,
                              hipStream_t stream) {
    const float* caps = (const float*)d_in[0];   // (64, 2048, 16)
    const float* W    = (const float*)d_in[1];   // (2048, 16, 256)
    float* out = (float*)d_out;                  // (64, 256)
    float* ws  = (float*)d_ws;

    // layout: Up packed = 8*PB @0 | X @8PB | Y @9PB | Sc @10PB  (~168 MB)
    unsigned* Up = (unsigned*)ws;
    unsigned short* Xh = (unsigned short*)(ws + (size_t)8 * PB);
    unsigned short* Xl = Xh + (size_t)NB * DDSQ;
    unsigned short* Yh = (unsigned short*)(ws + (size_t)9 * PB);
    unsigned short* Yl = Yh + (size_t)NB * DDSQ;
    float* Sc = ws + (size_t)10 * PB;

    hipMemsetAsync(Sc, 0, 2048 * sizeof(float), stream);

    u_kernel<<<IC, 256, 0, stream>>>(caps, W, Up);
    cm64_kernel<<<640, 256, 0, stream>>>(Up, Xh, Xl, Sc);  // C (unscaled) -> X

    unsigned short* ph = Xh; unsigned short* pl = Xl;
    unsigned short* qh = Yh; unsigned short* ql = Yl;
    for (int it = 0; it < NSQ; ++it) {
        sqm_kernel<<<640, 256, 0, stream>>>(ph, pl, qh, ql,
                                            Sc + it * 64, Sc + (it + 1) * 64);
        unsigned short* t1 = ph; ph = qh; qh = t1;
        unsigned short* t2 = pl; pl = ql; ql = t2;
    }

    finish_kernel<<<NB, 256, 0, stream>>>(ph, pl, out);
}

// Round 15
// 324.743 us; speedup vs baseline: 4.0249x; 1.1466x over previous
//
#include <hip/hip_runtime.h>

#define NB  64
#define IC  2048
#define ID  16
#define DD  256
#define DDSQ 65536
#define PB  (DDSQ * NB)       // 4,194,304 floats = one full-batch fp32-sized buffer
#define NSQ 11                // matrix squarings
#define NPI 7                 // finish matvecs: exponent 2^11 * 8 = 16384

typedef __attribute__((ext_vector_type(8))) short          s16x8;  // 8 bf16 (4 VGPRs) MFMA frag
typedef __attribute__((ext_vector_type(4))) float          f32x4;  // MFMA acc
typedef __attribute__((ext_vector_type(4))) unsigned short us4;
typedef __attribute__((ext_vector_type(8))) unsigned short us8;

// fp32 -> bf16 (RNE) and back, via raw bits
__device__ __forceinline__ unsigned short f2b(float f) {
    union { float f; unsigned u; } c; c.f = f;
    const unsigned u = c.u + 0x7FFFu + ((c.u >> 16) & 1u);
    return (unsigned short)(u >> 16);
}
__device__ __forceinline__ float b2f(unsigned short h) {
    union { unsigned u; float f; } c; c.u = ((unsigned)h) << 16;
    return c.f;
}
// fp32 -> packed (hi bf16 << 16) | (lo bf16): 2-term split in one u32
__device__ __forceinline__ unsigned f2pk(float f) {
    const unsigned short h = f2b(f);
    const unsigned short l = f2b(f - b2f(h));
    return ((unsigned)h << 16) | (unsigned)l;
}

// ---------------- stage 1: u[b,c,:] = x[b,c,:] @ W_c (ALL 64 batches/block) -
// One block per capsule c (2048 blocks): W row read ONCE (round-10 proven).
__global__ __launch_bounds__(256, 4) void u_kernel(const float* __restrict__ caps,
                                                   const float* __restrict__ W,
                                                   unsigned* __restrict__ U) {
    const int c = blockIdx.x;
    const int t = threadIdx.x;
    __shared__ float xsT[ID][64];        // [dim][batch] (4 KB)
    {
        const int b = t >> 2, q = (t & 3) * 4;
        const float4 x4 = *(const float4*)&caps[((size_t)b * IC + c) * ID + q];
        xsT[q + 0][b] = x4.x; xsT[q + 1][b] = x4.y;
        xsT[q + 2][b] = x4.z; xsT[q + 3][b] = x4.w;
    }
    __syncthreads();
    float a[64];
#pragma unroll
    for (int b = 0; b < 64; ++b) a[b] = 0.f;
#pragma unroll
    for (int i = 0; i < ID; ++i) {
        const float wi = W[((size_t)c * ID + i) * DD + t];    // coalesced over t
#pragma unroll
        for (int g = 0; g < 16; ++g) {
            const float4 x = *(const float4*)&xsT[i][g * 4];
            a[g * 4 + 0] = fmaf(x.x, wi, a[g * 4 + 0]);
            a[g * 4 + 1] = fmaf(x.y, wi, a[g * 4 + 1]);
            a[g * 4 + 2] = fmaf(x.z, wi, a[g * 4 + 2]);
            a[g * 4 + 3] = fmaf(x.w, wi, a[g * 4 + 3]);
        }
    }
#pragma unroll
    for (int b = 0; b < 64; ++b)
        U[((size_t)b * IC + c) * DD + t] = f2pk(a[b]);
}

// ---- stage 2: C = U^T U, 64x64 tiles, UPPER TRIANGLE (640 blocks) ----------
// EXACT round-14 body (C bit-exactly symmetric; mirror via transposed us4).
__global__ __launch_bounds__(256, 4)
void cm64_kernel(const unsigned* __restrict__ Up,
                 unsigned short* __restrict__ Ch, unsigned short* __restrict__ Cl,
                 float* __restrict__ Sc) {
    const int id   = blockIdx.x;          // 640 = 64 batches x 10 tri-tiles
    const int bb   = id & 63;
    const int tile = id >> 6;             // 0..9 upper-triangle enumeration
    int tr, tc;
    if (tile < 4)      { tr = 0; tc = tile; }
    else if (tile < 7) { tr = 1; tc = tile - 3; }
    else if (tile < 9) { tr = 2; tc = tile - 5; }
    else               { tr = 3; tc = 3; }
    const int d0 = tr * 64, e0 = tc * 64;
    const int t    = threadIdx.x;
    const int lane = t & 63, wid = t >> 6;
    const int wm = wid >> 1, wn = wid & 1;            // 2x2 wave grid, 32x32/wave
    const int fr = lane & 15, kg = lane >> 4;         // frag row, k-group
    const int sl8 = lane & 7, qg = lane >> 3;         // staging: row-in-octet, k-quad
    const size_t mb = (size_t)bb * DDSQ;

    __shared__ unsigned short Ah[64][40];   // [d][k], pitch 40 shorts (80 B)
    __shared__ unsigned short Al[64][40];
    __shared__ unsigned short Bh[64][40];   // [e][k]
    __shared__ unsigned short Bl[64][40];
    __shared__ float red[256];

    const f32x4 z4 = {0.f, 0.f, 0.f, 0.f};
    f32x4 acc[2][2];
#pragma unroll
    for (int m = 0; m < 2; ++m)
#pragma unroll
        for (int n = 0; n < 2; ++n) acc[m][n] = z4;

    const unsigned* Ub = Up + (size_t)bb * IC * DD;
    unsigned va[2][4], vb[2][4];
    auto loadU = [&](int kb) {
#pragma unroll
        for (int s = 0; s < 2; ++s) {
            const int row = wid * 8 + sl8 + 32 * s;       // d-local 0..63
#pragma unroll
            for (int j = 0; j < 4; ++j)
                va[s][j] = Ub[(size_t)(kb + 4 * qg + j) * DD + d0 + row];
        }
#pragma unroll
        for (int s = 0; s < 2; ++s) {
            const int row = wid * 8 + sl8 + 32 * s;       // e-local 0..63
#pragma unroll
            for (int j = 0; j < 4; ++j)
                vb[s][j] = Ub[(size_t)(kb + 4 * qg + j) * DD + e0 + row];
        }
    };

    loadU(0);
    for (int kb = 0; kb < IC; kb += 32) {
        __syncthreads();
#pragma unroll
        for (int s = 0; s < 2; ++s) {
            const int row = wid * 8 + sl8 + 32 * s;
            us4 h, l;
#pragma unroll
            for (int j = 0; j < 4; ++j) {
                h[j] = (unsigned short)(va[s][j] >> 16);
                l[j] = (unsigned short)(va[s][j] & 0xFFFFu);
            }
            *(us4*)&Ah[row][4 * qg] = h;
            *(us4*)&Al[row][4 * qg] = l;
        }
#pragma unroll
        for (int s = 0; s < 2; ++s) {
            const int row = wid * 8 + sl8 + 32 * s;
            us4 h, l;
#pragma unroll
            for (int j = 0; j < 4; ++j) {
                h[j] = (unsigned short)(vb[s][j] >> 16);
                l[j] = (unsigned short)(vb[s][j] & 0xFFFFu);
            }
            *(us4*)&Bh[row][4 * qg] = h;
            *(us4*)&Bl[row][4 * qg] = l;
        }
        __syncthreads();
        if (kb + 32 < IC) loadU(kb + 32);     // T14: next loads fly under MFMA
        s16x8 ah[2], al[2], bh[2], bl[2];
#pragma unroll
        for (int m = 0; m < 2; ++m) {
            const int r = wm * 32 + m * 16 + fr;
            ah[m] = *(const s16x8*)&Ah[r][kg * 8];
            al[m] = *(const s16x8*)&Al[r][kg * 8];
        }
#pragma unroll
        for (int n = 0; n < 2; ++n) {
            const int r = wn * 32 + n * 16 + fr;
            bh[n] = *(const s16x8*)&Bh[r][kg * 8];
            bl[n] = *(const s16x8*)&Bl[r][kg * 8];
        }
#pragma unroll
        for (int m = 0; m < 2; ++m)
#pragma unroll
            for (int n = 0; n < 2; ++n) {
                acc[m][n] = __builtin_amdgcn_mfma_f32_16x16x32_bf16(ah[m], bh[n], acc[m][n], 0, 0, 0);
                acc[m][n] = __builtin_amdgcn_mfma_f32_16x16x32_bf16(ah[m], bl[n], acc[m][n], 0, 0, 0);
                acc[m][n] = __builtin_amdgcn_mfma_f32_16x16x32_bf16(al[m], bh[n], acc[m][n], 0, 0, 0);
            }
    }

    // epilogue: bf16 hi/lo store (UNSCALED C) + trace; mirror off-diag tiles
    float ts = 0.f;
    const int row_l = wm * 32 + (lane >> 4) * 4;
    const int col_l = wn * 32 + fr;
    const bool mir = (tr != tc);
#pragma unroll
    for (int m = 0; m < 2; ++m)
#pragma unroll
        for (int n = 0; n < 2; ++n) {
            const int gr0 = d0 + row_l + m * 16;
            const int gc  = e0 + col_l + n * 16;
            us4 h4, l4;
#pragma unroll
            for (int r = 0; r < 4; ++r) {
                const float e = acc[m][n][r];
                const unsigned short h = f2b(e);
                const unsigned short l = f2b(e - b2f(h));
                const size_t o = mb + (size_t)(gr0 + r) * DD + gc;
                Ch[o] = h; Cl[o] = l;
                h4[r] = h; l4[r] = l;
                if (gr0 + r == gc) ts += e;
            }
            if (mir) {                    // transposed us4: row gc, cols gr0..+3
                const size_t o2 = mb + (size_t)gc * DD + gr0;
                *(us4*)&Ch[o2] = h4;
                *(us4*)&Cl[o2] = l4;
            }
        }
    if (tr == tc) {                       // 4 diag tiles partition the diagonal
        red[t] = ts;
        __syncthreads();
        for (int s2 = 128; s2 > 0; s2 >>= 1) {
            if (t < s2) red[t] += red[t + s2];
            __syncthreads();
        }
        if (t == 0) atomicAdd(&Sc[bb], red[0]);
    }
}

// ---- E = (D/s)^2, 64x64 tile, BK=64, UPPER-TRIANGLE ONLY (640 blocks) ------
// EXACT round-12/14-proven body (bit-identical output).
__global__ __launch_bounds__(256, 4)
void sqm_kernel(const unsigned short* __restrict__ Dh, const unsigned short* __restrict__ Dl,
                unsigned short* __restrict__ Eh, unsigned short* __restrict__ El,
                const float* __restrict__ s_in, float* __restrict__ s_out) {
    const int id   = blockIdx.x;          // 640 = 64 batches x 10 tri-tiles
    const int bb   = id & 63;             // id%8 == bb%8 -> batch XCD-local
    const int tile = id >> 6;             // 0..9 upper-triangle enumeration
    int tr, tc;
    if (tile < 4)      { tr = 0; tc = tile; }
    else if (tile < 7) { tr = 1; tc = tile - 3; }
    else if (tile < 9) { tr = 2; tc = tile - 5; }
    else               { tr = 3; tc = 3; }
    const int d0 = tr * 64, e0 = tc * 64;
    const int t    = threadIdx.x;
    const int lane = t & 63, wid = t >> 6;
    const int wm = wid >> 1, wn = wid & 1;            // 2x2 wave grid, 32x32/wave
    const int fr = lane & 15, kg = lane >> 4;
    const size_t mb = (size_t)bb * DDSQ;

    __shared__ unsigned short Ah[64][72];   // pitch 72 shorts (144 B)
    __shared__ unsigned short Al[64][72];
    __shared__ unsigned short Bh[64][72];
    __shared__ unsigned short Bl[64][72];
    __shared__ float red[256];

    const f32x4 z4 = {0.f, 0.f, 0.f, 0.f};
    f32x4 acc[2][2];
#pragma unroll
    for (int m = 0; m < 2; ++m)
#pragma unroll
        for (int n = 0; n < 2; ++n) acc[m][n] = z4;

    const float s   = s_in[bb];
    const float inv = 1.f / (s * s);
    const int row = t >> 2, q = t & 3;    // staging map: 64 rows x 4 k-quads

    for (int kb = 0; kb < DD; kb += 64) {
        const size_t ga = mb + (size_t)(d0 + row) * DD + kb + q * 8;
        const size_t gb = mb + (size_t)(e0 + row) * DD + kb + q * 8;
        const int4 rah0 = *(const int4*)&Dh[ga];
        const int4 rah1 = *(const int4*)&Dh[ga + 32];
        const int4 ral0 = *(const int4*)&Dl[ga];
        const int4 ral1 = *(const int4*)&Dl[ga + 32];
        const int4 rbh0 = *(const int4*)&Dh[gb];
        const int4 rbh1 = *(const int4*)&Dh[gb + 32];
        const int4 rbl0 = *(const int4*)&Dl[gb];
        const int4 rbl1 = *(const int4*)&Dl[gb + 32];
        __syncthreads();
        *(int4*)&Ah[row][q * 8]      = rah0;
        *(int4*)&Ah[row][q * 8 + 32] = rah1;
        *(int4*)&Al[row][q * 8]      = ral0;
        *(int4*)&Al[row][q * 8 + 32] = ral1;
        *(int4*)&Bh[row][q * 8]      = rbh0;
        *(int4*)&Bh[row][q * 8 + 32] = rbh1;
        *(int4*)&Bl[row][q * 8]      = rbl0;
        *(int4*)&Bl[row][q * 8 + 32] = rbl1;
        __syncthreads();

#pragma unroll
        for (int h = 0; h < 2; ++h) {
            const int ko = kg * 8 + 32 * h;
            s16x8 ah[2], al[2], bh[2], bl[2];
#pragma unroll
            for (int m = 0; m < 2; ++m) {
                const int r = wm * 32 + m * 16 + fr;
                ah[m] = *(const s16x8*)&Ah[r][ko];
                al[m] = *(const s16x8*)&Al[r][ko];
            }
#pragma unroll
            for (int n = 0; n < 2; ++n) {
                const int r = wn * 32 + n * 16 + fr;
                bh[n] = *(const s16x8*)&Bh[r][ko];
                bl[n] = *(const s16x8*)&Bl[r][ko];
            }
#pragma unroll
            for (int m = 0; m < 2; ++m)
#pragma unroll
                for (int n = 0; n < 2; ++n) {
                    acc[m][n] = __builtin_amdgcn_mfma_f32_16x16x32_bf16(ah[m], bh[n], acc[m][n], 0, 0, 0);
                    acc[m][n] = __builtin_amdgcn_mfma_f32_16x16x32_bf16(ah[m], bl[n], acc[m][n], 0, 0, 0);
                    acc[m][n] = __builtin_amdgcn_mfma_f32_16x16x32_bf16(al[m], bh[n], acc[m][n], 0, 0, 0);
                }
        }
    }

    // epilogue: scale, trace, split to hi/lo bf16; mirror off-diag tiles
    float ts = 0.f;
    const int row_l = wm * 32 + (lane >> 4) * 4;
    const int col_l = wn * 32 + fr;
    const bool mir = (tr != tc);
#pragma unroll
    for (int m = 0; m < 2; ++m)
#pragma unroll
        for (int n = 0; n < 2; ++n) {
            const int gr0 = d0 + row_l + m * 16;
            const int gc  = e0 + col_l + n * 16;
            us4 h4, l4;
#pragma unroll
            for (int r = 0; r < 4; ++r) {
                const float e = acc[m][n][r] * inv;
                const unsigned short h = f2b(e);
                const unsigned short l = f2b(e - b2f(h));
                const size_t o = mb + (size_t)(gr0 + r) * DD + gc;
                Eh[o] = h; El[o] = l;
                h4[r] = h; l4[r] = l;
                if (gr0 + r == gc) ts += e;
            }
            if (mir) {                    // transposed us4: row gc, cols gr0..+3
                const size_t o2 = mb + (size_t)gc * DD + gr0;
                *(us4*)&Eh[o2] = h4;
                *(us4*)&El[o2] = l4;
            }
        }
    if (tr == tc) {                       // 4 diag tiles partition the diagonal
        red[t] = ts;
        __syncthreads();
        for (int s2 = 128; s2 > 0; s2 >>= 1) {
            if (t < s2) red[t] += red[t + s2];
            __syncthreads();
        }
        if (t == 0) atomicAdd(&s_out[bb], red[0]);
    }
}

// ------- finish: 1024 threads/block (16 waves/CU) ---------------------------
// Old version: 256 threads, each walking a full 256-row serially => 64 blocks
// x 4 waves, Occupancy 2.6%, 71.5 us. Now thread (row=t>>2, q=t&3) does a
// 64-element quarter-row; 4 partials sit in adjacent lanes of one wave =>
// two width-4 __shfl_xor finish the dot. Critical path/matvec: 256 -> 64 MACs.
// Quarter-split reassociates the fp32 sum (pairwise, IEEE-commutative) —
// ~2^-24/step vs the bf16 matrix's 2^-18 floor: absmax unaffected at scale.
__global__ __launch_bounds__(1024, 1)
void finish_kernel(const unsigned short* __restrict__ Dh,
                   const unsigned short* __restrict__ Dl,
                   float* __restrict__ out) {
    const int b = blockIdx.x, t = threadIdx.x;
    const int row = t >> 2, q = t & 3;
    const size_t mb = (size_t)b * DDSQ;
    __shared__ float vs[DD];
    __shared__ float red[DD];
    __shared__ int   ridx[DD];
    if (t < DD) {
        red[t] = b2f(Dh[mb + (size_t)t * DD + t]) + b2f(Dl[mb + (size_t)t * DD + t]);
        ridx[t] = t;
    }
    __syncthreads();
    for (int s = 128; s > 0; s >>= 1) {
        if (t < s && red[t + s] > red[t]) { red[t] = red[t + s]; ridx[t] = ridx[t + s]; }
        __syncthreads();
    }
    const int jmax0 = ridx[0];
    __syncthreads();
    if (t < DD)
        vs[t] = b2f(Dh[mb + (size_t)jmax0 * DD + t]) + b2f(Dl[mb + (size_t)jmax0 * DD + t]);
    __syncthreads();

    const unsigned short* rh = Dh + mb + (size_t)row * DD + q * 64;
    const unsigned short* rl = Dl + mb + (size_t)row * DD + q * 64;
    for (int it = 0; it < NPI; ++it) {
        float a = 0.f;
        const float* vq = vs + q * 64;
#pragma unroll
        for (int j = 0; j < 64; j += 8) {
            const us8 h8 = *(const us8*)&rh[j];
            const us8 l8 = *(const us8*)&rl[j];
            a = fmaf(b2f(h8[0]) + b2f(l8[0]), vq[j + 0], a);
            a = fmaf(b2f(h8[1]) + b2f(l8[1]), vq[j + 1], a);
            a = fmaf(b2f(h8[2]) + b2f(l8[2]), vq[j + 2], a);
            a = fmaf(b2f(h8[3]) + b2f(l8[3]), vq[j + 3], a);
            a = fmaf(b2f(h8[4]) + b2f(l8[4]), vq[j + 4], a);
            a = fmaf(b2f(h8[5]) + b2f(l8[5]), vq[j + 5], a);
            a = fmaf(b2f(h8[6]) + b2f(l8[6]), vq[j + 6], a);
            a = fmaf(b2f(h8[7]) + b2f(l8[7]), vq[j + 7], a);
        }
        a += __shfl_xor(a, 1);            // q-pairs (same wave, lanes 4k..4k+3)
        a += __shfl_xor(a, 2);
        __syncthreads();                  // all reads of vs complete
        if (q == 0) vs[row] = a;
        __syncthreads();
    }

    if (t < DD) red[t] = vs[t] * vs[t];
    __syncthreads();
    for (int s = 128; s > 0; s >>= 1) {
        if (t < s) red[t] += red[t + s];
        __syncthreads();
    }
    const float nrm = sqrtf(red[0]);
    __syncthreads();
    if (t < DD) { red[t] = fabsf(vs[t]); ridx[t] = t; }
    __syncthreads();
    for (int s = 128; s > 0; s >>= 1) {
        if (t < s && red[t + s] > red[t]) { red[t] = red[t + s]; ridx[t] = ridx[t + s]; }
        __syncthreads();
    }
    const float sgn = (vs[ridx[0]] < 0.f) ? -1.f : 1.f;
    if (t < DD) out[(size_t)b * DD + t] = sgn * vs[t] / nrm;
}

extern "C" void kernel_launch(void* const* d_in, const int* in_sizes, int n_in,
                              void* d_out, int out_size, void* d_ws, size_t ws_size,
                              hipStream_t stream) {
    const float* caps = (const float*)d_in[0];   // (64, 2048, 16)
    const float* W    = (const float*)d_in[1];   // (2048, 16, 256)
    float* out = (float*)d_out;                  // (64, 256)
    float* ws  = (float*)d_ws;

    // layout: Up packed = 8*PB @0 | X @8PB | Y @9PB | Sc @10PB  (~168 MB)
    unsigned* Up = (unsigned*)ws;
    unsigned short* Xh = (unsigned short*)(ws + (size_t)8 * PB);
    unsigned short* Xl = Xh + (size_t)NB * DDSQ;
    unsigned short* Yh = (unsigned short*)(ws + (size_t)9 * PB);
    unsigned short* Yl = Yh + (size_t)NB * DDSQ;
    float* Sc = ws + (size_t)10 * PB;

    hipMemsetAsync(Sc, 0, 2048 * sizeof(float), stream);

    u_kernel<<<IC, 256, 0, stream>>>(caps, W, Up);
    cm64_kernel<<<640, 256, 0, stream>>>(Up, Xh, Xl, Sc);  // C (unscaled) -> X

    unsigned short* ph = Xh; unsigned short* pl = Xl;
    unsigned short* qh = Yh; unsigned short* ql = Yl;
    for (int it = 0; it < NSQ; ++it) {
        sqm_kernel<<<640, 256, 0, stream>>>(ph, pl, qh, ql,
                                            Sc + it * 64, Sc + (it + 1) * 64);
        unsigned short* t1 = ph; ph = qh; qh = t1;
        unsigned short* t2 = pl; pl = ql; ql = t2;
    }

    finish_kernel<<<NB, 1024, 0, stream>>>(ph, pl, out);
}